// Round 10
// baseline (201.859 us; speedup 1.0000x reference)
//
#include <hip/hip_runtime.h>
#include <hip/hip_bf16.h>
#include <stdint.h>

#define N_NODES   16384
#define DIMM      256
#define HEADS     8
#define HDIM      32
#define NUM_GLOBAL 4
#define N_TOT     (N_NODES + NUM_GLOBAL)   // 16388
#define E_LOCAL   131072
#define E_EXP     65536
#define E_CSR     (E_LOCAL + E_EXP)        // 196608

typedef __hip_bfloat16 bf16;
typedef __attribute__((ext_vector_type(8))) short short8;
typedef __attribute__((ext_vector_type(4))) short sh4;
typedef __attribute__((ext_vector_type(4))) float f32x4;

__device__ __forceinline__ short f2s(float f) {
    bf16 h = __float2bfloat16(f);
    return __builtin_bit_cast(short, h);
}
__device__ __forceinline__ float bu2f(unsigned short u) {
    return __bfloat162float(__builtin_bit_cast(bf16, u));
}

// XOR swizzle: 16B chunk c of row r stored at chunk (c ^ (r&7) ^ ((r>>3)&7)).
__device__ __forceinline__ int swz(int c, int r) {
    return c ^ (r & 7) ^ ((r >> 3) & 7);
}

// ---------------------------------------------------------------------------
// QKV projection (MFMA): X_full(16388x256 fp32) @ Wqkv(256x768 fp32) + b.
// Q -> fp32; K,V -> bf16. Tile 128x64 (BM x BN), BK=64, 4 waves; wave w
// computes rows [w*32,w*32+32) x all 64 cols via 2x4 frags of 16x16x32.
// 24 KB LDS + 1548 blocks -> ~6 blocks/CU for latency hiding (R9 had 774
// blocks @32KB -> 23% occupancy, everything idle).
// ---------------------------------------------------------------------------
__global__ __launch_bounds__(256) void qkv_mfma(
    const float* __restrict__ x, const float* __restrict__ gtok,
    const float* __restrict__ W, const float* __restrict__ bias,
    float* __restrict__ Q, bf16* __restrict__ Kb, bf16* __restrict__ Vb)
{
    __shared__ short As[128 * 64];   // [m][k] bf16, swizzled 16B chunks
    __shared__ short Bs[64 * 64];    // [n][k] bf16 (B^T), swizzled
    const int t  = threadIdx.x;
    const int m0 = blockIdx.y * 128;
    const int n0 = blockIdx.x * 64;            // 0..704
    const int w = t >> 6, lane = t & 63;
    const int lm = lane & 15, lq = lane >> 4;

    f32x4 acc[2][4] = {};

    for (int k0 = 0; k0 < DIMM; k0 += 64) {
        if (k0) __syncthreads();
        // --- stage A: 128 rows x 64 k; 4 short8 chunks per thread ---
        #pragma unroll
        for (int i = 0; i < 4; ++i) {
            int c8 = t + 256 * i;
            int r  = c8 >> 3, kc = c8 & 7;
            int row = m0 + r;
            float4 v0 = make_float4(0.f, 0.f, 0.f, 0.f), v1 = v0;
            if (row < N_NODES) {
                const float* p = x + (size_t)row * DIMM + k0 + kc * 8;
                v0 = *(const float4*)p; v1 = *(const float4*)(p + 4);
            } else if (row < N_TOT) {
                const float* p = gtok + (size_t)(row - N_NODES) * DIMM + k0 + kc * 8;
                v0 = *(const float4*)p; v1 = *(const float4*)(p + 4);
            }
            short8 o;
            o[0] = f2s(v0.x); o[1] = f2s(v0.y); o[2] = f2s(v0.z); o[3] = f2s(v0.w);
            o[4] = f2s(v1.x); o[5] = f2s(v1.y); o[6] = f2s(v1.z); o[7] = f2s(v1.w);
            *(short8*)(As + r * 64 + swz(kc, r) * 8) = o;
        }
        // --- stage B^T: 64 k x 64 n; thread = (4 k-rows) x (4 cols) ---
        {
            const int kg = t >> 4;             // 0..15 -> k rows kg*4..+3
            const int ng = t & 15;             // 0..15 -> cols ng*4..+3
            float4 wv[4];
            #pragma unroll
            for (int rr = 0; rr < 4; ++rr)
                wv[rr] = *(const float4*)(W + (size_t)(k0 + kg * 4 + rr) * 768 + n0 + ng * 4);
            const int c = kg >> 1, half = (kg & 1) * 4;
            #pragma unroll
            for (int j = 0; j < 4; ++j) {
                int n = ng * 4 + j;
                sh4 o;
                o[0] = f2s(j == 0 ? wv[0].x : j == 1 ? wv[0].y : j == 2 ? wv[0].z : wv[0].w);
                o[1] = f2s(j == 0 ? wv[1].x : j == 1 ? wv[1].y : j == 2 ? wv[1].z : wv[1].w);
                o[2] = f2s(j == 0 ? wv[2].x : j == 1 ? wv[2].y : j == 2 ? wv[2].z : wv[2].w);
                o[3] = f2s(j == 0 ? wv[3].x : j == 1 ? wv[3].y : j == 2 ? wv[3].z : wv[3].w);
                *(sh4*)(Bs + n * 64 + swz(c, n) * 8 + half) = o;
            }
        }
        __syncthreads();
        // --- MFMA: 2 k-blocks of 32; quad lq holds k-chunk (kk*4+lq) ---
        #pragma unroll
        for (int kk = 0; kk < 2; ++kk) {
            const int c = kk * 4 + lq;
            short8 af[2], bfq[4];
            #pragma unroll
            for (int mi = 0; mi < 2; ++mi) {
                int r = w * 32 + mi * 16 + lm;
                af[mi] = *(const short8*)(As + r * 64 + swz(c, r) * 8);
            }
            #pragma unroll
            for (int ni = 0; ni < 4; ++ni) {
                int n = ni * 16 + lm;
                bfq[ni] = *(const short8*)(Bs + n * 64 + swz(c, n) * 8);
            }
            #pragma unroll
            for (int mi = 0; mi < 2; ++mi)
                #pragma unroll
                for (int ni = 0; ni < 4; ++ni)
                    acc[mi][ni] = __builtin_amdgcn_mfma_f32_16x16x32_bf16(
                        af[mi], bfq[ni], acc[mi][ni], 0, 0, 0);
        }
    }

    // --- epilogue: C col = lm, row = lq*4+rr; n0 is 64-wide -> one of Q/K/V
    const int sel = n0 >> 8;                 // 0=Q 1=K 2=V
    #pragma unroll
    for (int ni = 0; ni < 4; ++ni) {
        int col = n0 + ni * 16 + lm;
        float bv = bias[col];
        int cc = col & 255;
        #pragma unroll
        for (int mi = 0; mi < 2; ++mi) {
            int rowb = m0 + w * 32 + mi * 16 + lq * 4;
            #pragma unroll
            for (int rr = 0; rr < 4; ++rr) {
                int row = rowb + rr;
                if (row >= N_TOT) continue;
                float val = acc[mi][ni][rr] + bv;
                if (sel == 0)      Q [(size_t)row * DIMM + cc] = val;
                else if (sel == 1) Kb[(size_t)row * DIMM + cc] = __float2bfloat16(val);
                else               Vb[(size_t)row * DIMM + cc] = __float2bfloat16(val);
            }
        }
    }
}

// ---------------------------------------------------------------------------
// Output projection (MFMA): O(16384x256 bf16) @ Wout(256x256 fp32->bf16)
// + bout -> out fp32. Same 128x64 tile structure; grid 4x128 = 512 blocks.
// ---------------------------------------------------------------------------
__global__ __launch_bounds__(256) void out_mfma(
    const bf16* __restrict__ O, const float* __restrict__ W,
    const float* __restrict__ bias, float* __restrict__ out)
{
    __shared__ short As[128 * 64];
    __shared__ short Bs[64 * 64];
    const int t  = threadIdx.x;
    const int m0 = blockIdx.y * 128;
    const int n0 = blockIdx.x * 64;            // 0..192
    const int w = t >> 6, lane = t & 63;
    const int lm = lane & 15, lq = lane >> 4;

    f32x4 acc[2][4] = {};

    for (int k0 = 0; k0 < DIMM; k0 += 64) {
        if (k0) __syncthreads();
        // --- stage A: direct bf16 copy, 4 short8 per thread ---
        #pragma unroll
        for (int i = 0; i < 4; ++i) {
            int c8 = t + 256 * i;
            int r  = c8 >> 3, kc = c8 & 7;
            short8 v = *(const short8*)((const short*)O + (size_t)(m0 + r) * DIMM + k0 + kc * 8);
            *(short8*)(As + r * 64 + swz(kc, r) * 8) = v;
        }
        // --- stage B^T ---
        {
            const int kg = t >> 4;
            const int ng = t & 15;
            float4 wv[4];
            #pragma unroll
            for (int rr = 0; rr < 4; ++rr)
                wv[rr] = *(const float4*)(W + (size_t)(k0 + kg * 4 + rr) * DIMM + n0 + ng * 4);
            const int c = kg >> 1, half = (kg & 1) * 4;
            #pragma unroll
            for (int j = 0; j < 4; ++j) {
                int n = ng * 4 + j;
                sh4 o;
                o[0] = f2s(j == 0 ? wv[0].x : j == 1 ? wv[0].y : j == 2 ? wv[0].z : wv[0].w);
                o[1] = f2s(j == 0 ? wv[1].x : j == 1 ? wv[1].y : j == 2 ? wv[1].z : wv[1].w);
                o[2] = f2s(j == 0 ? wv[2].x : j == 1 ? wv[2].y : j == 2 ? wv[2].z : wv[2].w);
                o[3] = f2s(j == 0 ? wv[3].x : j == 1 ? wv[3].y : j == 2 ? wv[3].z : wv[3].w);
                *(sh4*)(Bs + n * 64 + swz(c, n) * 8 + half) = o;
            }
        }
        __syncthreads();
        #pragma unroll
        for (int kk = 0; kk < 2; ++kk) {
            const int c = kk * 4 + lq;
            short8 af[2], bfq[4];
            #pragma unroll
            for (int mi = 0; mi < 2; ++mi) {
                int r = w * 32 + mi * 16 + lm;
                af[mi] = *(const short8*)(As + r * 64 + swz(c, r) * 8);
            }
            #pragma unroll
            for (int ni = 0; ni < 4; ++ni) {
                int n = ni * 16 + lm;
                bfq[ni] = *(const short8*)(Bs + n * 64 + swz(c, n) * 8);
            }
            #pragma unroll
            for (int mi = 0; mi < 2; ++mi)
                #pragma unroll
                for (int ni = 0; ni < 4; ++ni)
                    acc[mi][ni] = __builtin_amdgcn_mfma_f32_16x16x32_bf16(
                        af[mi], bfq[ni], acc[mi][ni], 0, 0, 0);
        }
    }

    #pragma unroll
    for (int ni = 0; ni < 4; ++ni) {
        int col = n0 + ni * 16 + lm;
        float bv = bias[col];
        #pragma unroll
        for (int mi = 0; mi < 2; ++mi) {
            int rowb = m0 + w * 32 + mi * 16 + lq * 4;
            #pragma unroll
            for (int rr = 0; rr < 4; ++rr) {
                float val = acc[mi][ni][rr] + bv;
                val = fminf(fmaxf(val, -1e4f), 1e4f);  // tripwire (no-op valid)
                out[(size_t)(rowb + rr) * DIMM + col] = val;
            }
        }
    }
}

// ---------------------------------------------------------------------------
// CSR build (dst-keyed) for local+expander edges. n2g edges skipped (their
// outputs are discarded by the reference's out[:N]).
// ---------------------------------------------------------------------------
__global__ void count_edges(const int* __restrict__ ei, const int* __restrict__ xei,
                            int* __restrict__ cnt)
{
    int e = blockIdx.x * blockDim.x + threadIdx.x;
    if (e < E_LOCAL) {
        atomicAdd(&cnt[ei[E_LOCAL + e]], 1);
    } else if (e < E_CSR) {
        int ee = e - E_LOCAL;
        atomicAdd(&cnt[xei[E_EXP + ee]], 1);
    }
}

__global__ void scan_kernel(int* __restrict__ cnt_cursor, int* __restrict__ rowstart)
{
    __shared__ int part[256];
    const int t = threadIdx.x;
    const int base = t * 64;
    int s = 0;
    for (int i = 0; i < 64; ++i) s += cnt_cursor[base + i];
    part[t] = s;
    __syncthreads();
    for (int off = 1; off < 256; off <<= 1) {
        int v = (t >= off) ? part[t - off] : 0;
        __syncthreads();
        part[t] += v;
        __syncthreads();
    }
    int excl = part[t] - s;
    for (int i = 0; i < 64; ++i) {
        int v = cnt_cursor[base + i];
        rowstart[base + i]   = excl;
        cnt_cursor[base + i] = excl;
        excl += v;
    }
    if (t == 255) rowstart[N_NODES] = excl;
}

__global__ void fill_edges(const int* __restrict__ ei, const int* __restrict__ xei,
                           int* __restrict__ cursor, int* __restrict__ adj)
{
    int e = blockIdx.x * blockDim.x + threadIdx.x;
    int s, d;
    if (e < E_LOCAL)      { s = ei[e];            d = ei[E_LOCAL + e]; }
    else if (e < E_CSR)   { int ee = e - E_LOCAL; s = xei[ee]; d = xei[E_EXP + ee]; }
    else return;
    int pos = atomicAdd(&cursor[d], 1);
    adj[pos] = s;
}

// ---------------------------------------------------------------------------
// Gather attention: one wave per dst node; bf16 K/V; 4-edge unroll so 8
// gather loads are in flight per iteration (VALUBusy was 14% -> loop is
// load-latency-serialized). Virtual edge index domain [rs-5, re):
// -5=self, -4..-1=globals, >=0 = adj[i]. Tripwires are no-ops on valid data.
// ---------------------------------------------------------------------------
__global__ __launch_bounds__(256) void attn_kernel(
    const float* __restrict__ Q, const bf16* __restrict__ Kb,
    const bf16* __restrict__ Vb, const int* __restrict__ rowstart,
    const int* __restrict__ adj, bf16* __restrict__ Ob)
{
    const int wave = (blockIdx.x * blockDim.x + threadIdx.x) >> 6;
    const int lane = threadIdx.x & 63;
    if (wave >= N_NODES) return;
    const int n = wave;
    const float scale = 0.1767766952966369f;  // 32^-0.5

    const ushort4* K4 = (const ushort4*)Kb;
    const ushort4* V4 = (const ushort4*)Vb;

    float4 q = ((const float4*)(Q + (size_t)n * DIMM))[lane];
    q.x *= scale; q.y *= scale; q.z *= scale; q.w *= scale;

    float4 acc = make_float4(0.f, 0.f, 0.f, 0.f);
    float dsum = 0.f;

    const int rs = rowstart[n];
    const int re = rowstart[n + 1];

    for (int i = rs - 5; i < re; i += 4) {
        int   sv[4];
        float ok[4];
        #pragma unroll
        for (int u = 0; u < 4; ++u) {
            int ii = i + u;
            bool v = (ii < re);
            int d = ii - rs;
            int s = v ? ((d < 0) ? ((d == -5) ? n : (N_NODES + d + 4)) : adj[ii]) : 0;
            sv[u] = min(max(s, 0), N_TOT - 1);
            ok[u] = v ? 1.f : 0.f;
        }
        ushort4 kv[4], vv[4];
        #pragma unroll
        for (int u = 0; u < 4; ++u) kv[u] = K4[(size_t)sv[u] * 64 + lane];
        #pragma unroll
        for (int u = 0; u < 4; ++u) vv[u] = V4[(size_t)sv[u] * 64 + lane];

        float p[4];
        #pragma unroll
        for (int u = 0; u < 4; ++u)
            p[u] = q.x * bu2f(kv[u].x) + q.y * bu2f(kv[u].y)
                 + q.z * bu2f(kv[u].z) + q.w * bu2f(kv[u].w);
        #pragma unroll
        for (int u = 0; u < 4; ++u) {
            p[u] += __shfl_xor(p[u], 1);
            p[u] += __shfl_xor(p[u], 2);
            p[u] += __shfl_xor(p[u], 4);     // head score in all 8 lanes
        }
        #pragma unroll
        for (int u = 0; u < 4; ++u) {
            float wgt = ok[u] * __expf(fminf(p[u], 80.f));
            dsum += wgt;
            acc.x += wgt * bu2f(vv[u].x);
            acc.y += wgt * bu2f(vv[u].y);
            acc.z += wgt * bu2f(vv[u].z);
            acc.w += wgt * bu2f(vv[u].w);
        }
    }

    float r = 1.0f / fmaxf(dsum, 1e-30f);    // tripwire
    ushort4 o;
    o.x = (unsigned short)__builtin_bit_cast(short, __float2bfloat16(fminf(fmaxf(acc.x * r, -500.f), 500.f)));
    o.y = (unsigned short)__builtin_bit_cast(short, __float2bfloat16(fminf(fmaxf(acc.y * r, -500.f), 500.f)));
    o.z = (unsigned short)__builtin_bit_cast(short, __float2bfloat16(fminf(fmaxf(acc.z * r, -500.f), 500.f)));
    o.w = (unsigned short)__builtin_bit_cast(short, __float2bfloat16(fminf(fmaxf(acc.w * r, -500.f), 500.f)));
    ((ushort4*)Ob)[(size_t)n * 64 + lane] = o;
}

// ---------------------------------------------------------------------------
extern "C" void kernel_launch(void* const* d_in, const int* in_sizes, int n_in,
                              void* d_out, int out_size, void* d_ws, size_t ws_size,
                              hipStream_t stream)
{
    const float* x    = (const float*)d_in[0];
    const int*   ei   = (const int*)d_in[1];
    const int*   xei  = (const int*)d_in[2];
    const float* Wqkv = (const float*)d_in[3];
    const float* bqkv = (const float*)d_in[4];
    const float* Wout = (const float*)d_in[5];
    const float* bout = (const float*)d_in[6];
    const float* gtok = (const float*)d_in[7];

    // workspace layout (~43.3 MB):
    int* rowstart = (int*)d_ws;               // N_NODES+1
    int* cursor   = rowstart + (N_NODES + 1); // N_NODES
    int* adj      = cursor + N_NODES;         // E_CSR
    const size_t int_bytes = (size_t)(N_NODES + 1 + N_NODES + E_CSR) * sizeof(int);
    uintptr_t fb = ((uintptr_t)(adj + E_CSR) + 15) & ~(uintptr_t)15;
    float* Q  = (float*)fb;                        // fp32, N_TOT*256
    bf16*  Kb = (bf16*)(Q + (size_t)N_TOT * DIMM); // bf16, N_TOT*256
    bf16*  Vb = Kb + (size_t)N_TOT * DIMM;         // bf16, N_TOT*256
    bf16*  Ob = Vb + (size_t)N_TOT * DIMM;         // bf16, N_NODES*256

    hipMemsetAsync(d_ws, 0, int_bytes, stream);

    qkv_mfma<<<dim3(12, 129), 256, 0, stream>>>(x, gtok, Wqkv, bqkv, Q, Kb, Vb);
    count_edges<<<(E_CSR + 255) / 256, 256, 0, stream>>>(ei, xei, cursor);
    scan_kernel<<<1, 256, 0, stream>>>(cursor, rowstart);
    fill_edges<<<(E_CSR + 255) / 256, 256, 0, stream>>>(ei, xei, cursor, adj);
    attn_kernel<<<N_NODES / 4, 256, 0, stream>>>(Q, Kb, Vb, rowstart, adj, Ob);
    out_mfma<<<dim3(4, 128), 256, 0, stream>>>(Ob, Wout, bout, (float*)d_out);
}